// Round 13
// baseline (316.840 us; speedup 1.0000x reference)
//
#include <hip/hip_runtime.h>
#include <hip/hip_bf16.h>
#include <math.h>

#define B_ 4
#define N_ 1024
#define D_ 1024
#define E_ 8
#define H_ 2730
#define H2_ 5460
#define CAP_ 256
#define NTOK 4096
#define NSLOT 8192
#define NKT1 16      // K-tiles (BK=64) for GEMM1 buffers
#define NKT2 43      // K-tiles (BK=64) for GEMM2
#define NFG 22       // 128-wide f-col groups (pad 2816)

typedef __attribute__((ext_vector_type(8))) short short8;
typedef __attribute__((ext_vector_type(4))) float f32x4;

__device__ __forceinline__ unsigned short f2bf(float f) {
    __hip_bfloat16 h = __float2bfloat16(f);
    return *reinterpret_cast<unsigned short*>(&h);
}
__device__ __forceinline__ float bf2f(unsigned short u) {
    unsigned x = ((unsigned)u) << 16;
    union { unsigned u; float f; } c; c.u = x; return c.f;
}

#define MFMA16(a, b, c) __builtin_amdgcn_mfma_f32_16x16x32_bf16((a), (b), (c), 0, 0, 0)
#define LD8(p) (*reinterpret_cast<const short8*>(p))

// ============ fragment-packed layouts (bytes unchanged) ============
// A chunk (per (sgrp,kt64), 16384 ush): off = k32*8192 + m16*512 + lane*8 + b
// B1 chunk (per (e,fg,kt64), 16384 ush): off = k32*8192 + n16*512 + lane*8 + b ; n16 0..7 val, 8..15 gate
// B2 chunk (per (e,nt,kt64), 8192 ush):  off = k32*4096 + n16*512 + lane*8 + b

// ---------------- cvt1: w1 f32 -> fragment-packed bf16 (LDS-transpose) ----------------
__global__ __launch_bounds__(256) void k_cvt1(const float* __restrict__ w1,
                                              unsigned short* __restrict__ w1p) {
    const int fg = blockIdx.x;   // 0..21
    const int kt = blockIdx.y;   // 0..15
    const int e  = blockIdx.z;
    const float* w1e = w1 + (size_t)e * D_ * H2_;
    unsigned short* dst = w1p + (((size_t)((e * NFG + fg) * NKT1 + kt)) << 14);
    __shared__ unsigned short tile[128][66];
    const int t = threadIdx.x;
    const int fl4 = (t & 31) * 4;
    const int kr  = t >> 5;
    const int fbase = fg * 128;

    for (int m = 0; m < 2; ++m) {
        if (m) __syncthreads();
        const int c0 = m * H_;
#pragma unroll
        for (int ii = 0; ii < 8; ++ii) {
            const int kl = ii * 8 + kr;
            const float* src = w1e + (size_t)(kt * 64 + kl) * H2_ + c0 + fbase + fl4;
            float v0, v1, v2, v3;
            if (fbase + fl4 + 3 < H_) {
                const float4 v = *reinterpret_cast<const float4*>(src);
                v0 = v.x; v1 = v.y; v2 = v.z; v3 = v.w;
            } else {
                v0 = (fbase + fl4 + 0 < H_) ? src[0] : 0.f;
                v1 = (fbase + fl4 + 1 < H_) ? src[1] : 0.f;
                v2 = (fbase + fl4 + 2 < H_) ? src[2] : 0.f;
                v3 = (fbase + fl4 + 3 < H_) ? src[3] : 0.f;
            }
            tile[fl4 + 0][kl] = f2bf(v0);
            tile[fl4 + 1][kl] = f2bf(v1);
            tile[fl4 + 2][kl] = f2bf(v2);
            tile[fl4 + 3][kl] = f2bf(v3);
        }
        __syncthreads();
#pragma unroll
        for (int i = 0; i < 4; ++i) {
            const int o = i * 256 + t;
            const int k32  = o >> 9;
            const int flhi = (o >> 6) & 7;
            const int lane = o & 63;
            const int kq   = lane >> 4;
            const int fl   = flhi * 16 + (lane & 15);
            const int kb   = k32 * 32 + kq * 8;
            const unsigned* rp = reinterpret_cast<const unsigned*>(&tile[fl][kb]);
            uint4 q; q.x = rp[0]; q.y = rp[1]; q.z = rp[2]; q.w = rp[3];
            const size_t off = ((size_t)k32 << 13) + (size_t)(m * 8 + flhi) * 512 + (size_t)lane * 8;
            *reinterpret_cast<uint4*>(dst + off) = q;
        }
    }
}

// ---------------- cvt2: w2 f32 -> fragment-packed bf16 (LDS-transpose) ----------------
__global__ __launch_bounds__(256) void k_cvt2(const float* __restrict__ w2,
                                              unsigned short* __restrict__ w2p) {
    const int kt = blockIdx.x;   // 0..42
    const int nt = blockIdx.y;   // 0..7
    const int e  = blockIdx.z;
    const float* w2e = w2 + (size_t)e * H_ * D_;
    unsigned short* dst = w2p + (((size_t)((e * 8 + nt) * NKT2 + kt)) << 13);
    __shared__ unsigned short tile[128][66];
    const int t = threadIdx.x;
    const int d4 = (t & 31) * 4;
    const int fr = t >> 5;

#pragma unroll
    for (int ii = 0; ii < 8; ++ii) {
        const int fl = ii * 8 + fr;
        const int f = kt * 64 + fl;
        float v0 = 0.f, v1 = 0.f, v2 = 0.f, v3 = 0.f;
        if (f < H_) {
            const float4 v = *reinterpret_cast<const float4*>(w2e + (size_t)f * D_ + nt * 128 + d4);
            v0 = v.x; v1 = v.y; v2 = v.z; v3 = v.w;
        }
        tile[d4 + 0][fl] = f2bf(v0);
        tile[d4 + 1][fl] = f2bf(v1);
        tile[d4 + 2][fl] = f2bf(v2);
        tile[d4 + 3][fl] = f2bf(v3);
    }
    __syncthreads();
#pragma unroll
    for (int i = 0; i < 4; ++i) {
        const int o = i * 256 + t;
        const int k32 = o >> 9;
        const int dhi = (o >> 6) & 7;
        const int lane = o & 63;
        const int kq = lane >> 4;
        const int dl = dhi * 16 + (lane & 15);
        const int fb = k32 * 32 + kq * 8;
        const unsigned* rp = reinterpret_cast<const unsigned*>(&tile[dl][fb]);
        uint4 q; q.x = rp[0]; q.y = rp[1]; q.z = rp[2]; q.w = rp[3];
        const size_t off = ((size_t)k32 << 12) + (size_t)dhi * 512 + (size_t)lane * 8;
        *reinterpret_cast<uint4*>(dst + off) = q;
    }
}

// ---------------- gating (gw as 2x float4/lane; inits sot) ----------------
__global__ __launch_bounds__(256) void k_gate(const float* __restrict__ x,
                                              const float* __restrict__ route,
                                              const float* __restrict__ gw,
                                              int* __restrict__ tokE,
                                              float* __restrict__ tokG,
                                              int* __restrict__ tokR,
                                              int* __restrict__ sot) {
    const int wave = threadIdx.x >> 6, lane = threadIdx.x & 63;
    const int t = blockIdx.x * 4 + wave;
    float acc[E_];
#pragma unroll
    for (int e = 0; e < E_; ++e) acc[e] = 0.f;
    const float* xr = x + (size_t)t * D_;
    for (int d = lane; d < D_; d += 64) {
        const float xv = xr[d];
        const float4 g0 = *reinterpret_cast<const float4*>(gw + d * 8);
        const float4 g1 = *reinterpret_cast<const float4*>(gw + d * 8 + 4);
        acc[0] = fmaf(xv, g0.x, acc[0]); acc[1] = fmaf(xv, g0.y, acc[1]);
        acc[2] = fmaf(xv, g0.z, acc[2]); acc[3] = fmaf(xv, g0.w, acc[3]);
        acc[4] = fmaf(xv, g1.x, acc[4]); acc[5] = fmaf(xv, g1.y, acc[5]);
        acc[6] = fmaf(xv, g1.z, acc[6]); acc[7] = fmaf(xv, g1.w, acc[7]);
    }
#pragma unroll
    for (int e = 0; e < E_; ++e) {
#pragma unroll
        for (int off = 32; off; off >>= 1) acc[e] += __shfl_xor(acc[e], off);
    }
    if (lane == 0) {
        float m = acc[0];
#pragma unroll
        for (int e = 1; e < E_; ++e) m = fmaxf(m, acc[e]);
        float p[E_]; float s = 0.f;
#pragma unroll
        for (int e = 0; e < E_; ++e) { p[e] = expf(acc[e] - m); s += p[e]; }
        int i0 = 0; float v0 = p[0];
#pragma unroll
        for (int e = 1; e < E_; ++e) if (p[e] > v0) { v0 = p[e]; i0 = e; }
        int i1 = (i0 == 0) ? 1 : 0; float v1 = p[i1];
#pragma unroll
        for (int e = 0; e < E_; ++e) if (e != i0 && p[e] > v1) { v1 = p[e]; i1 = e; }
        float p0 = v0 / s, p1 = v1 / s;
        float denom = fmaxf(p0 + p1, 1e-9f);
        float g0 = p0 / denom, g1 = p1 / denom;
        int r1 = route[NTOK + t] < (g1 / 0.2f);
        tokE[t] = i0; tokE[NTOK + t] = i1;
        tokG[t] = g0; tokG[NTOK + t] = g1;
        tokR[t] = r1;
        sot[t] = -1; sot[NTOK + t] = -1;
    }
}

// ---------------- positions (inits its own tos range) ----------------
__global__ __launch_bounds__(256) void k_pos(const int* __restrict__ tokE,
                                             const float* __restrict__ tokG,
                                             const int* __restrict__ tokR,
                                             int* __restrict__ sot,
                                             int* __restrict__ tos) {
    const int e = blockIdx.x & 7, b = blockIdx.x >> 3;
    const int t = threadIdx.x;
    __shared__ int sc[256];
    tos[((e * B_ + b) << 8) + t] = -1;     // own 256-slot range; barriers below order it
    const int base_bt = b * N_ + t * 4;
    int m0[4], m1[4];
    int c0 = 0, c1 = 0;
#pragma unroll
    for (int i = 0; i < 4; ++i) {
        int bt = base_bt + i;
        m0[i] = (tokE[bt] == e) ? 1 : 0;
        m1[i] = ((tokE[NTOK + bt] == e) && tokR[bt]) ? 1 : 0;
        c0 += m0[i]; c1 += m1[i];
    }
    int packed = c0 | (c1 << 16);
    sc[t] = packed;
    __syncthreads();
    for (int off = 1; off < 256; off <<= 1) {
        int v = (t >= off) ? sc[t - off] : 0;
        __syncthreads();
        sc[t] += v;
        __syncthreads();
    }
    int incl = sc[t];
    int total = sc[255];
    int excl = incl - packed;
    int base0 = excl & 0xffff;
    int base1 = excl >> 16;
    int kept0 = min(total & 0xffff, CAP_);
#pragma unroll
    for (int i = 0; i < 4; ++i) {
        int bt = base_bt + i;
        if (m0[i]) {
            int pos = base0++;
            if (pos < CAP_ && tokG[bt] > 0.f) {
                int s = ((e * B_ + b) << 8) + pos;
                sot[bt] = s;
                tos[s] = bt;
            }
        }
        if (m1[i]) {
            int pos = (base1++) + kept0;
            if (pos < CAP_ && tokG[NTOK + bt] > 0.f) {
                int s = ((e * B_ + b) << 8) + pos;
                sot[NTOK + bt] = s;
                tos[s] = bt;
            }
        }
    }
}

// ---------------- dispatch ----------------
__global__ __launch_bounds__(256) void k_disp(const float* __restrict__ x,
                                              const int* __restrict__ tos,
                                              unsigned short* __restrict__ xeP) {
    const int t = threadIdx.x;
    const int s = blockIdx.x * 2 + (t >> 7);
    const int q = t & 127;
    const int bt = tos[s];
    const int kt = q >> 3, k32 = (q >> 2) & 1, kq = q & 3;
    const int lane = (kq << 4) | (s & 15);
    const int m16 = (s >> 4) & 15;
    const int sgrp = s >> 8;
    unsigned short* dst = xeP + (((size_t)(sgrp * NKT1 + kt)) << 14) + (k32 << 13) + (m16 << 9) + lane * 8;
    ushort4 r0 = {0, 0, 0, 0}, r1 = {0, 0, 0, 0};
    if (bt >= 0) {
        const float4 v0 = *reinterpret_cast<const float4*>(x + ((size_t)bt << 10) + q * 8);
        const float4 v1 = *reinterpret_cast<const float4*>(x + ((size_t)bt << 10) + q * 8 + 4);
        r0.x = f2bf(v0.x); r0.y = f2bf(v0.y); r0.z = f2bf(v0.z); r0.w = f2bf(v0.w);
        r1.x = f2bf(v1.x); r1.y = f2bf(v1.y); r1.z = f2bf(v1.z); r1.w = f2bf(v1.w);
    }
    *reinterpret_cast<ushort4*>(dst) = r0;
    *reinterpret_cast<ushort4*>(dst + 4) = r1;
}

// ---------------- GEMM1 + GEGLU: LDS-free, barrier-free, VGPR-dbuf ----------------
// wave = (wm 0-1, wn 0-3): rows wm*128+[0,128), cols fg*128 + wn*32 + [0,32) x {val,gate}
#define LOADG1(P, G)                                                          \
    do {                                                                      \
        const unsigned short* ap = aw + (size_t)(G) * 8192;                   \
        const unsigned short* bp = bw + (size_t)(G) * 8192;                   \
        P##A0 = LD8(ap);        P##A1 = LD8(ap + 512);                        \
        P##A2 = LD8(ap + 1024); P##A3 = LD8(ap + 1536);                       \
        P##A4 = LD8(ap + 2048); P##A5 = LD8(ap + 2560);                       \
        P##A6 = LD8(ap + 3072); P##A7 = LD8(ap + 3584);                       \
        P##V0 = LD8(bp);        P##V1 = LD8(bp + 512);                        \
        P##G0 = LD8(bp + 4096); P##G1 = LD8(bp + 4608);                       \
    } while (0)

#define MFMAG1(P)                                                             \
    do {                                                                      \
        __builtin_amdgcn_s_setprio(1);                                        \
        acc[0][0]=MFMA16(P##A0,P##V0,acc[0][0]); acc[0][1]=MFMA16(P##A0,P##V1,acc[0][1]); \
        acc[0][2]=MFMA16(P##A0,P##G0,acc[0][2]); acc[0][3]=MFMA16(P##A0,P##G1,acc[0][3]); \
        acc[1][0]=MFMA16(P##A1,P##V0,acc[1][0]); acc[1][1]=MFMA16(P##A1,P##V1,acc[1][1]); \
        acc[1][2]=MFMA16(P##A1,P##G0,acc[1][2]); acc[1][3]=MFMA16(P##A1,P##G1,acc[1][3]); \
        acc[2][0]=MFMA16(P##A2,P##V0,acc[2][0]); acc[2][1]=MFMA16(P##A2,P##V1,acc[2][1]); \
        acc[2][2]=MFMA16(P##A2,P##G0,acc[2][2]); acc[2][3]=MFMA16(P##A2,P##G1,acc[2][3]); \
        acc[3][0]=MFMA16(P##A3,P##V0,acc[3][0]); acc[3][1]=MFMA16(P##A3,P##V1,acc[3][1]); \
        acc[3][2]=MFMA16(P##A3,P##G0,acc[3][2]); acc[3][3]=MFMA16(P##A3,P##G1,acc[3][3]); \
        acc[4][0]=MFMA16(P##A4,P##V0,acc[4][0]); acc[4][1]=MFMA16(P##A4,P##V1,acc[4][1]); \
        acc[4][2]=MFMA16(P##A4,P##G0,acc[4][2]); acc[4][3]=MFMA16(P##A4,P##G1,acc[4][3]); \
        acc[5][0]=MFMA16(P##A5,P##V0,acc[5][0]); acc[5][1]=MFMA16(P##A5,P##V1,acc[5][1]); \
        acc[5][2]=MFMA16(P##A5,P##G0,acc[5][2]); acc[5][3]=MFMA16(P##A5,P##G1,acc[5][3]); \
        acc[6][0]=MFMA16(P##A6,P##V0,acc[6][0]); acc[6][1]=MFMA16(P##A6,P##V1,acc[6][1]); \
        acc[6][2]=MFMA16(P##A6,P##G0,acc[6][2]); acc[6][3]=MFMA16(P##A6,P##G1,acc[6][3]); \
        acc[7][0]=MFMA16(P##A7,P##V0,acc[7][0]); acc[7][1]=MFMA16(P##A7,P##V1,acc[7][1]); \
        acc[7][2]=MFMA16(P##A7,P##G0,acc[7][2]); acc[7][3]=MFMA16(P##A7,P##G1,acc[7][3]); \
        __builtin_amdgcn_s_setprio(0);                                        \
    } while (0)

__global__ __launch_bounds__(512) void k_ffn1(const unsigned short* __restrict__ xeP,
                                              const unsigned short* __restrict__ w1p,
                                              const float* __restrict__ b1,
                                              const float* __restrict__ mbias,
                                              unsigned short* __restrict__ actP) {
    const int wg = blockIdx.x;               // 704 = 8 XCD * 88
    const int e = wg & 7;
    const int rem = wg >> 3;
    const int fg = rem >> 2;                 // 0..21
    const int rt = rem & 3;                  // 0..3
    const int sgrp = e * 4 + rt;

    const int tid = threadIdx.x, lane = tid & 63, w = tid >> 6;
    const int wm = w >> 2, wn = w & 3;
    const int lane8 = lane * 8;

    const unsigned short* aw = xeP + ((size_t)(sgrp * NKT1) << 14) + (wm * 8) * 512 + lane8;
    const unsigned short* bw = w1p + ((size_t)((e * NFG + fg) * NKT1) << 14) + (wn * 2) * 512 + lane8;

    f32x4 acc[8][4];
#pragma unroll
    for (int i = 0; i < 8; ++i)
#pragma unroll
        for (int j = 0; j < 4; ++j) acc[i][j] = (f32x4)(0.f);

    short8 cA0, cA1, cA2, cA3, cA4, cA5, cA6, cA7, cV0, cV1, cG0, cG1;
    short8 nA0, nA1, nA2, nA3, nA4, nA5, nA6, nA7, nV0, nV1, nG0, nG1;

    LOADG1(c, 0);
    for (int g = 0; g < 32; g += 2) {        // 32 ks-groups (16 kt x 2)
        LOADG1(n, g + 1);
        MFMAG1(c);
        if (g + 2 < 32) LOADG1(c, g + 2);
        MFMAG1(n);
    }

    // epilogue: bias + exact GELU + mult_bias -> fragment-packed act
    const float* b1e = b1 + (size_t)e * H2_;
    const float* mbe = mbias + (size_t)e * H_;
    const int colL = lane & 15, rq4 = (lane >> 4) * 4;
#pragma unroll
    for (int mi = 0; mi < 8; ++mi) {
        const int Rl = wm * 128 + mi * 16 + rq4;
#pragma unroll
        for (int vi = 0; vi < 2; ++vi) {
            const int f = fg * 128 + wn * 32 + vi * 16 + colL;
            if (f >= NKT2 * 64) continue;
            const bool real = f < H_;
            const float bv = real ? b1e[f] : 0.f;
            const float bg = real ? b1e[H_ + f] : 0.f;
            const float mv = real ? mbe[f] : 0.f;
            const int ktf = f >> 6, k32f = (f >> 5) & 1;
            const int lhi = ((f >> 3) & 3) << 4;
            const int bb = f & 7;
            const size_t cbase = ((size_t)(sgrp * NKT2 + ktf) << 14) + (k32f << 13);
#pragma unroll
            for (int j = 0; j < 4; ++j) {
                const int R = Rl + j;
                float a = 0.f;
                if (real) {
                    const float val = acc[mi][vi][j] + bv;
                    const float gt  = acc[mi][2 + vi][j] + bg;
                    a = 0.5f * gt * (1.f + erff(gt * 0.70710678118654752f)) * val * mv;
                }
                actP[cbase + ((R >> 4) << 9) + (size_t)((lhi | (R & 15)) * 8 + bb)] = f2bf(a);
            }
        }
    }
}

// ---------------- GEMM2: LDS-free, barrier-free, VGPR-dbuf ----------------
#define LOADG2(P, G)                                                          \
    do {                                                                      \
        const unsigned short* ap = aw + (size_t)(G) * 8192;                   \
        const unsigned short* bp = bw + (size_t)(G) * 4096;                   \
        P##A0 = LD8(ap);        P##A1 = LD8(ap + 512);                        \
        P##A2 = LD8(ap + 1024); P##A3 = LD8(ap + 1536);                       \
        P##A4 = LD8(ap + 2048); P##A5 = LD8(ap + 2560);                       \
        P##A6 = LD8(ap + 3072); P##A7 = LD8(ap + 3584);                       \
        P##B0 = LD8(bp);        P##B1 = LD8(bp + 512);                        \
    } while (0)

#define MFMAG2(P)                                                             \
    do {                                                                      \
        __builtin_amdgcn_s_setprio(1);                                        \
        acc[0][0]=MFMA16(P##A0,P##B0,acc[0][0]); acc[0][1]=MFMA16(P##A0,P##B1,acc[0][1]); \
        acc[1][0]=MFMA16(P##A1,P##B0,acc[1][0]); acc[1][1]=MFMA16(P##A1,P##B1,acc[1][1]); \
        acc[2][0]=MFMA16(P##A2,P##B0,acc[2][0]); acc[2][1]=MFMA16(P##A2,P##B1,acc[2][1]); \
        acc[3][0]=MFMA16(P##A3,P##B0,acc[3][0]); acc[3][1]=MFMA16(P##A3,P##B1,acc[3][1]); \
        acc[4][0]=MFMA16(P##A4,P##B0,acc[4][0]); acc[4][1]=MFMA16(P##A4,P##B1,acc[4][1]); \
        acc[5][0]=MFMA16(P##A5,P##B0,acc[5][0]); acc[5][1]=MFMA16(P##A5,P##B1,acc[5][1]); \
        acc[6][0]=MFMA16(P##A6,P##B0,acc[6][0]); acc[6][1]=MFMA16(P##A6,P##B1,acc[6][1]); \
        acc[7][0]=MFMA16(P##A7,P##B0,acc[7][0]); acc[7][1]=MFMA16(P##A7,P##B1,acc[7][1]); \
        __builtin_amdgcn_s_setprio(0);                                        \
    } while (0)

__global__ __launch_bounds__(512) void k_ffn2(const unsigned short* __restrict__ actP,
                                              const unsigned short* __restrict__ w2p,
                                              const float* __restrict__ b2,
                                              unsigned short* __restrict__ oute) {
    const int wg = blockIdx.x;               // 256 = 8 XCD * 32
    const int e = wg & 7;
    const int rem = wg >> 3;
    const int nt = rem >> 2;                 // 0..7
    const int mt = rem & 3;                  // 0..3
    const int sgrp = e * 4 + mt;

    const int tid = threadIdx.x, lane = tid & 63, w = tid >> 6;
    const int wm = w >> 2, wn = w & 3;
    const int lane8 = lane * 8;

    const unsigned short* aw = actP + ((size_t)(sgrp * NKT2) << 14) + (wm * 8) * 512 + lane8;
    const unsigned short* bw = w2p + ((size_t)((e * 8 + nt) * NKT2) << 13) + (wn * 2) * 512 + lane8;

    f32x4 acc[8][2];
#pragma unroll
    for (int i = 0; i < 8; ++i)
#pragma unroll
        for (int j = 0; j < 2; ++j) acc[i][j] = (f32x4)(0.f);

    short8 cA0, cA1, cA2, cA3, cA4, cA5, cA6, cA7, cB0, cB1;
    short8 nA0, nA1, nA2, nA3, nA4, nA5, nA6, nA7, nB0, nB1;

    LOADG2(c, 0);
    for (int g = 0; g < 86; g += 2) {        // 86 ks-groups (43 kt x 2)
        LOADG2(n, g + 1);
        MFMAG2(c);
        if (g + 2 < 86) LOADG2(c, g + 2);
        MFMAG2(n);
    }

    const float* b2e = b2 + (size_t)e * D_;
    const int colL = lane & 15, rq4 = (lane >> 4) * 4;
#pragma unroll
    for (int mi = 0; mi < 8; ++mi) {
#pragma unroll
        for (int vi = 0; vi < 2; ++vi) {
            const int d = nt * 128 + wn * 32 + vi * 16 + colL;
            const float bb2 = b2e[d];
#pragma unroll
            for (int j = 0; j < 4; ++j) {
                const int R = mt * 256 + wm * 128 + mi * 16 + rq4 + j;
                oute[((size_t)(e * 1024 + R) << 10) + d] = f2bf(acc[mi][vi][j] + bb2);
            }
        }
    }
}

// ---------------- combine (bf16 oute) ----------------
__global__ __launch_bounds__(256) void k_comb(const unsigned short* __restrict__ oute,
                                              const int* __restrict__ sot,
                                              const float* __restrict__ tokG,
                                              float* __restrict__ out) {
    const int bt = blockIdx.x;
    const int t = threadIdx.x;
    const int s0 = sot[bt], s1 = sot[NTOK + bt];
    const float g0 = tokG[bt], g1 = tokG[NTOK + bt];
    float r0 = 0.f, r1 = 0.f, r2 = 0.f, r3 = 0.f;
    if (s0 >= 0) {
        const ushort4 v = *reinterpret_cast<const ushort4*>(oute + ((size_t)s0 << 10) + t * 4);
        r0 += g0 * bf2f(v.x); r1 += g0 * bf2f(v.y); r2 += g0 * bf2f(v.z); r3 += g0 * bf2f(v.w);
    }
    if (s1 >= 0) {
        const ushort4 v = *reinterpret_cast<const ushort4*>(oute + ((size_t)s1 << 10) + t * 4);
        r0 += g1 * bf2f(v.x); r1 += g1 * bf2f(v.y); r2 += g1 * bf2f(v.z); r3 += g1 * bf2f(v.w);
    }
    float4 o; o.x = r0; o.y = r1; o.z = r2; o.w = r3;
    *reinterpret_cast<float4*>(out + ((size_t)bt << 10) + t * 4) = o;
}

extern "C" void kernel_launch(void* const* d_in, const int* in_sizes, int n_in,
                              void* d_out, int out_size, void* d_ws, size_t ws_size,
                              hipStream_t stream) {
    const float* x     = (const float*)d_in[0];
    const float* route = (const float*)d_in[1];
    const float* gw    = (const float*)d_in[2];
    const float* w1    = (const float*)d_in[3];
    const float* b1    = (const float*)d_in[4];
    const float* mb    = (const float*)d_in[5];
    const float* w2    = (const float*)d_in[6];
    const float* b2    = (const float*)d_in[7];
    float* out = (float*)d_out;

    char* ws = (char*)d_ws;
    int*   tokE = (int*)(ws + 0);
    float* tokG = (float*)(ws + 32768);
    int*   tokR = (int*)(ws + 65536);
    int*   sot  = (int*)(ws + 81920);
    int*   tos  = (int*)(ws + 114688);
    unsigned short* xeP  = (unsigned short*)(ws + 147456);      // 16.78 MB, end 16,924,672
    unsigned short* actP = (unsigned short*)(ws + 16924672);    // 45.09 MB, end 62,013,440
    unsigned short* w1p  = (unsigned short*)(ws + 62013440);    // 92.27 MB, end 154,288,128 (dead after ffn1)
    unsigned short* w2p  = (unsigned short*)(ws + 62013440);    // 45.09 MB overlay (written after ffn1)
    unsigned short* oute = (unsigned short*)(ws + 107102208);   // 16.78 MB overlay, end 123,879,424

    k_cvt1<<<dim3(NFG, NKT1, 8), 256, 0, stream>>>(w1, w1p);
    k_gate<<<NTOK / 4, 256, 0, stream>>>(x, route, gw, tokE, tokG, tokR, sot);
    k_pos<<<E_ * B_, 256, 0, stream>>>(tokE, tokG, tokR, sot, tos);
    k_disp<<<NSLOT / 2, 256, 0, stream>>>(x, tos, xeP);
    k_ffn1<<<704, 512, 0, stream>>>(xeP, w1p, b1, mb, actP);
    k_cvt2<<<dim3(NKT2, 8, 8), 256, 0, stream>>>(w2, w2p);      // after ffn1: w2p overlays w1p
    k_ffn2<<<256, 512, 0, stream>>>(actP, w2p, b2, oute);
    k_comb<<<NTOK, 256, 0, stream>>>(oute, sot, tokG, out);
}

// Round 14
// 298.304 us; speedup vs baseline: 1.0621x; 1.0621x over previous
//
#include <hip/hip_runtime.h>
#include <hip/hip_bf16.h>
#include <math.h>

#define B_ 4
#define N_ 1024
#define D_ 1024
#define E_ 8
#define H_ 2730
#define H2_ 5460
#define CAP_ 256
#define NTOK 4096
#define NSLOT 8192
#define NKT1 16      // K-tiles for GEMM1 (K=1024, BK=64)
#define NKT2 43      // K-tiles for GEMM2 (K=2752, BK=64)
#define NFG 22       // 128-wide f-col groups (pad 2816)

typedef __attribute__((ext_vector_type(8))) short short8;
typedef __attribute__((ext_vector_type(4))) float f32x4;

__device__ __forceinline__ unsigned short f2bf(float f) {
    __hip_bfloat16 h = __float2bfloat16(f);
    return *reinterpret_cast<unsigned short*>(&h);
}
__device__ __forceinline__ float bf2f(unsigned short u) {
    unsigned x = ((unsigned)u) << 16;
    union { unsigned u; float f; } c; c.u = x; return c.f;
}

// async global(16B/lane) -> LDS (wave-uniform base + lane*16)
#define GLL16(g, l)                                                          \
    __builtin_amdgcn_global_load_lds(                                        \
        (const __attribute__((address_space(1))) void*)(g),                  \
        (__attribute__((address_space(3))) void*)(l), 16, 0, 0)

#define VMCNT4() asm volatile("s_waitcnt vmcnt(4)" ::: "memory")
#define VMCNT3() asm volatile("s_waitcnt vmcnt(3)" ::: "memory")
#define VMCNT0() asm volatile("s_waitcnt vmcnt(0)" ::: "memory")
#define SBAR()   __builtin_amdgcn_s_barrier()
#define SCHEDB() __builtin_amdgcn_sched_barrier(0)
#define MFMA16(a, b, c) __builtin_amdgcn_mfma_f32_16x16x32_bf16((a), (b), (c), 0, 0, 0)

// ============ fragment-packed layouts ============
// A chunk (per (sgrp,kt), 16384 ush = 32KB): off = k32*8192 + m16*512 + lane*8 + b
// B1 chunk (per (e,fg,kt), 16384 ush): off = k32*8192 + n16*512 + lane*8 + b ; n16 0..7 val, 8..15 gate
// B2 chunk (per (e,nt,kt), 8192 ush):  off = k32*4096 + n16*512 + lane*8 + b

// ---------------- cvt1: w1 f32 -> fragment-packed bf16 (LDS-transpose, float4 loads) ----------------
__global__ __launch_bounds__(256) void k_cvt1(const float* __restrict__ w1,
                                              unsigned short* __restrict__ w1p) {
    const int fg = blockIdx.x;   // 0..21
    const int kt = blockIdx.y;   // 0..15
    const int e  = blockIdx.z;
    const float* w1e = w1 + (size_t)e * D_ * H2_;
    unsigned short* dst = w1p + (((size_t)((e * NFG + fg) * NKT1 + kt)) << 14);
    __shared__ unsigned short tile[128][66];
    const int t = threadIdx.x;
    const int fl4 = (t & 31) * 4;
    const int kr  = t >> 5;
    const int fbase = fg * 128;

    for (int m = 0; m < 2; ++m) {
        if (m) __syncthreads();
        const int c0 = m * H_;
#pragma unroll
        for (int ii = 0; ii < 8; ++ii) {
            const int kl = ii * 8 + kr;
            const float* src = w1e + (size_t)(kt * 64 + kl) * H2_ + c0 + fbase + fl4;
            float v0, v1, v2, v3;
            if (fbase + fl4 + 3 < H_) {
                const float4 v = *reinterpret_cast<const float4*>(src);
                v0 = v.x; v1 = v.y; v2 = v.z; v3 = v.w;
            } else {
                v0 = (fbase + fl4 + 0 < H_) ? src[0] : 0.f;
                v1 = (fbase + fl4 + 1 < H_) ? src[1] : 0.f;
                v2 = (fbase + fl4 + 2 < H_) ? src[2] : 0.f;
                v3 = (fbase + fl4 + 3 < H_) ? src[3] : 0.f;
            }
            tile[fl4 + 0][kl] = f2bf(v0);
            tile[fl4 + 1][kl] = f2bf(v1);
            tile[fl4 + 2][kl] = f2bf(v2);
            tile[fl4 + 3][kl] = f2bf(v3);
        }
        __syncthreads();
#pragma unroll
        for (int i = 0; i < 4; ++i) {
            const int o = i * 256 + t;
            const int k32  = o >> 9;
            const int flhi = (o >> 6) & 7;
            const int lane = o & 63;
            const int kq   = lane >> 4;
            const int fl   = flhi * 16 + (lane & 15);
            const int kb   = k32 * 32 + kq * 8;
            const unsigned* rp = reinterpret_cast<const unsigned*>(&tile[fl][kb]);
            uint4 q; q.x = rp[0]; q.y = rp[1]; q.z = rp[2]; q.w = rp[3];
            const size_t off = ((size_t)k32 << 13) + (size_t)(m * 8 + flhi) * 512 + (size_t)lane * 8;
            *reinterpret_cast<uint4*>(dst + off) = q;
        }
    }
}

// ---------------- cvt2: w2 f32 -> fragment-packed bf16 (LDS-transpose, float4 loads) ----------------
__global__ __launch_bounds__(256) void k_cvt2(const float* __restrict__ w2,
                                              unsigned short* __restrict__ w2p) {
    const int kt = blockIdx.x;   // 0..42
    const int nt = blockIdx.y;   // 0..7
    const int e  = blockIdx.z;
    const float* w2e = w2 + (size_t)e * H_ * D_;
    unsigned short* dst = w2p + (((size_t)((e * 8 + nt) * NKT2 + kt)) << 13);
    __shared__ unsigned short tile[128][66];
    const int t = threadIdx.x;
    const int d4 = (t & 31) * 4;
    const int fr = t >> 5;

#pragma unroll
    for (int ii = 0; ii < 8; ++ii) {
        const int fl = ii * 8 + fr;
        const int f = kt * 64 + fl;
        float v0 = 0.f, v1 = 0.f, v2 = 0.f, v3 = 0.f;
        if (f < H_) {
            const float4 v = *reinterpret_cast<const float4*>(w2e + (size_t)f * D_ + nt * 128 + d4);
            v0 = v.x; v1 = v.y; v2 = v.z; v3 = v.w;
        }
        tile[d4 + 0][fl] = f2bf(v0);
        tile[d4 + 1][fl] = f2bf(v1);
        tile[d4 + 2][fl] = f2bf(v2);
        tile[d4 + 3][fl] = f2bf(v3);
    }
    __syncthreads();
#pragma unroll
    for (int i = 0; i < 4; ++i) {
        const int o = i * 256 + t;
        const int k32 = o >> 9;
        const int dhi = (o >> 6) & 7;
        const int lane = o & 63;
        const int kq = lane >> 4;
        const int dl = dhi * 16 + (lane & 15);
        const int fb = k32 * 32 + kq * 8;
        const unsigned* rp = reinterpret_cast<const unsigned*>(&tile[dl][fb]);
        uint4 q; q.x = rp[0]; q.y = rp[1]; q.z = rp[2]; q.w = rp[3];
        const size_t off = ((size_t)k32 << 12) + (size_t)dhi * 512 + (size_t)lane * 8;
        *reinterpret_cast<uint4*>(dst + off) = q;
    }
}

// ---------------- gating (float4 gw loads; inits sot) ----------------
__global__ __launch_bounds__(256) void k_gate(const float* __restrict__ x,
                                              const float* __restrict__ route,
                                              const float* __restrict__ gw,
                                              int* __restrict__ tokE,
                                              float* __restrict__ tokG,
                                              int* __restrict__ tokR,
                                              int* __restrict__ sot) {
    const int wave = threadIdx.x >> 6, lane = threadIdx.x & 63;
    const int t = blockIdx.x * 4 + wave;
    float acc[E_];
#pragma unroll
    for (int e = 0; e < E_; ++e) acc[e] = 0.f;
    const float* xr = x + (size_t)t * D_;
    for (int d = lane; d < D_; d += 64) {
        const float xv = xr[d];
        const float4 g0 = *reinterpret_cast<const float4*>(gw + d * 8);
        const float4 g1 = *reinterpret_cast<const float4*>(gw + d * 8 + 4);
        acc[0] = fmaf(xv, g0.x, acc[0]); acc[1] = fmaf(xv, g0.y, acc[1]);
        acc[2] = fmaf(xv, g0.z, acc[2]); acc[3] = fmaf(xv, g0.w, acc[3]);
        acc[4] = fmaf(xv, g1.x, acc[4]); acc[5] = fmaf(xv, g1.y, acc[5]);
        acc[6] = fmaf(xv, g1.z, acc[6]); acc[7] = fmaf(xv, g1.w, acc[7]);
    }
#pragma unroll
    for (int e = 0; e < E_; ++e) {
#pragma unroll
        for (int off = 32; off; off >>= 1) acc[e] += __shfl_xor(acc[e], off);
    }
    if (lane == 0) {
        float m = acc[0];
#pragma unroll
        for (int e = 1; e < E_; ++e) m = fmaxf(m, acc[e]);
        float p[E_]; float s = 0.f;
#pragma unroll
        for (int e = 0; e < E_; ++e) { p[e] = expf(acc[e] - m); s += p[e]; }
        int i0 = 0; float v0 = p[0];
#pragma unroll
        for (int e = 1; e < E_; ++e) if (p[e] > v0) { v0 = p[e]; i0 = e; }
        int i1 = (i0 == 0) ? 1 : 0; float v1 = p[i1];
#pragma unroll
        for (int e = 0; e < E_; ++e) if (e != i0 && p[e] > v1) { v1 = p[e]; i1 = e; }
        float p0 = v0 / s, p1 = v1 / s;
        float denom = fmaxf(p0 + p1, 1e-9f);
        float g0 = p0 / denom, g1 = p1 / denom;
        int r1 = route[NTOK + t] < (g1 / 0.2f);
        tokE[t] = i0; tokE[NTOK + t] = i1;
        tokG[t] = g0; tokG[NTOK + t] = g1;
        tokR[t] = r1;
        sot[t] = -1; sot[NTOK + t] = -1;
    }
}

// ---------------- positions (inits its own tos range) ----------------
__global__ __launch_bounds__(256) void k_pos(const int* __restrict__ tokE,
                                             const float* __restrict__ tokG,
                                             const int* __restrict__ tokR,
                                             int* __restrict__ sot,
                                             int* __restrict__ tos) {
    const int e = blockIdx.x & 7, b = blockIdx.x >> 3;
    const int t = threadIdx.x;
    __shared__ int sc[256];
    tos[((e * B_ + b) << 8) + t] = -1;     // own 256-slot range; barriers below order it
    const int base_bt = b * N_ + t * 4;
    int m0[4], m1[4];
    int c0 = 0, c1 = 0;
#pragma unroll
    for (int i = 0; i < 4; ++i) {
        int bt = base_bt + i;
        m0[i] = (tokE[bt] == e) ? 1 : 0;
        m1[i] = ((tokE[NTOK + bt] == e) && tokR[bt]) ? 1 : 0;
        c0 += m0[i]; c1 += m1[i];
    }
    int packed = c0 | (c1 << 16);
    sc[t] = packed;
    __syncthreads();
    for (int off = 1; off < 256; off <<= 1) {
        int v = (t >= off) ? sc[t - off] : 0;
        __syncthreads();
        sc[t] += v;
        __syncthreads();
    }
    int incl = sc[t];
    int total = sc[255];
    int excl = incl - packed;
    int base0 = excl & 0xffff;
    int base1 = excl >> 16;
    int kept0 = min(total & 0xffff, CAP_);
#pragma unroll
    for (int i = 0; i < 4; ++i) {
        int bt = base_bt + i;
        if (m0[i]) {
            int pos = base0++;
            if (pos < CAP_ && tokG[bt] > 0.f) {
                int s = ((e * B_ + b) << 8) + pos;
                sot[bt] = s;
                tos[s] = bt;
            }
        }
        if (m1[i]) {
            int pos = (base1++) + kept0;
            if (pos < CAP_ && tokG[NTOK + bt] > 0.f) {
                int s = ((e * B_ + b) << 8) + pos;
                sot[NTOK + bt] = s;
                tos[s] = bt;
            }
        }
    }
}

// ---------------- dispatch: gather x rows -> fragment-packed bf16 xe ----------------
__global__ __launch_bounds__(256) void k_disp(const float* __restrict__ x,
                                              const int* __restrict__ tos,
                                              unsigned short* __restrict__ xeP) {
    const int t = threadIdx.x;
    const int s = blockIdx.x * 2 + (t >> 7);
    const int q = t & 127;                   // k-octet index
    const int bt = tos[s];
    const int kt = q >> 3, k32 = (q >> 2) & 1, kq = q & 3;
    const int lane = (kq << 4) | (s & 15);
    const int m16 = (s >> 4) & 15;
    const int sgrp = s >> 8;
    unsigned short* dst = xeP + (((size_t)(sgrp * NKT1 + kt)) << 14) + (k32 << 13) + (m16 << 9) + lane * 8;
    ushort4 r0 = {0, 0, 0, 0}, r1 = {0, 0, 0, 0};
    if (bt >= 0) {
        const float4 v0 = *reinterpret_cast<const float4*>(x + ((size_t)bt << 10) + q * 8);
        const float4 v1 = *reinterpret_cast<const float4*>(x + ((size_t)bt << 10) + q * 8 + 4);
        r0.x = f2bf(v0.x); r0.y = f2bf(v0.y); r0.z = f2bf(v0.z); r0.w = f2bf(v0.w);
        r1.x = f2bf(v1.x); r1.y = f2bf(v1.y); r1.z = f2bf(v1.z); r1.w = f2bf(v1.w);
    }
    *reinterpret_cast<ushort4*>(dst) = r0;
    *reinterpret_cast<ushort4*>(dst + 4) = r1;
}

// ---------------- GEMM1 + GEGLU: distinct-buffer dbuf, counted-vmcnt (measured best) ----------------
#define LDF(BUF, idx) (*reinterpret_cast<const short8*>(&BUF[(idx) * 512 + lane8]))

#define FFN1_MM03(AF0, AF1, AF2, AF3)                                         \
    do {                                                                      \
        acc[0][0]=MFMA16(AF0,bf0,acc[0][0]); acc[0][1]=MFMA16(AF0,bf1,acc[0][1]); \
        acc[0][2]=MFMA16(AF0,bf2,acc[0][2]); acc[0][3]=MFMA16(AF0,bf3,acc[0][3]); \
        acc[1][0]=MFMA16(AF1,bf0,acc[1][0]); acc[1][1]=MFMA16(AF1,bf1,acc[1][1]); \
        acc[1][2]=MFMA16(AF1,bf2,acc[1][2]); acc[1][3]=MFMA16(AF1,bf3,acc[1][3]); \
        acc[2][0]=MFMA16(AF2,bf0,acc[2][0]); acc[2][1]=MFMA16(AF2,bf1,acc[2][1]); \
        acc[2][2]=MFMA16(AF2,bf2,acc[2][2]); acc[2][3]=MFMA16(AF2,bf3,acc[2][3]); \
        acc[3][0]=MFMA16(AF3,bf0,acc[3][0]); acc[3][1]=MFMA16(AF3,bf1,acc[3][1]); \
        acc[3][2]=MFMA16(AF3,bf2,acc[3][2]); acc[3][3]=MFMA16(AF3,bf3,acc[3][3]); \
    } while (0)
#define FFN1_MM47(AF0, AF1, AF2, AF3)                                         \
    do {                                                                      \
        acc[4][0]=MFMA16(AF0,bf0,acc[4][0]); acc[4][1]=MFMA16(AF0,bf1,acc[4][1]); \
        acc[4][2]=MFMA16(AF0,bf2,acc[4][2]); acc[4][3]=MFMA16(AF0,bf3,acc[4][3]); \
        acc[5][0]=MFMA16(AF1,bf0,acc[5][0]); acc[5][1]=MFMA16(AF1,bf1,acc[5][1]); \
        acc[5][2]=MFMA16(AF1,bf2,acc[5][2]); acc[5][3]=MFMA16(AF1,bf3,acc[5][3]); \
        acc[6][0]=MFMA16(AF2,bf0,acc[6][0]); acc[6][1]=MFMA16(AF2,bf1,acc[6][1]); \
        acc[6][2]=MFMA16(AF2,bf2,acc[6][2]); acc[6][3]=MFMA16(AF2,bf3,acc[6][3]); \
        acc[7][0]=MFMA16(AF3,bf0,acc[7][0]); acc[7][1]=MFMA16(AF3,bf1,acc[7][1]); \
        acc[7][2]=MFMA16(AF3,bf2,acc[7][2]); acc[7][3]=MFMA16(AF3,bf3,acc[7][3]); \
    } while (0)

#define FFN1_KT(ARD, BRD, AWR, BWR, KTN, PF)                                  \
    do {                                                                      \
        const unsigned short* asn = abase + ((size_t)(KTN) << 14);            \
        const unsigned short* bsn = bbase + ((size_t)(KTN) << 14);            \
        short8 af0, af1, af2, af3, bf0, bf1, bf2, bf3;                        \
        SCHEDB(); VMCNT4(); SBAR(); SCHEDB();                                 \
        if (PF) {                                                             \
            GLL16(asn + woff + lane8, (char*)&AWR[woff]);                     \
            GLL16(asn + woff + 512 + lane8, (char*)&AWR[woff + 512]);         \
        }                                                                     \
        bf0 = LDF(BRD, bn0); bf1 = LDF(BRD, bn0 + 1);                         \
        bf2 = LDF(BRD, bn0 + 8); bf3 = LDF(BRD, bn0 + 9);                     \
        af0 = LDF(ARD, am0 + 0); af1 = LDF(ARD, am0 + 1);                     \
        af2 = LDF(ARD, am0 + 2); af3 = LDF(ARD, am0 + 3);                     \
        __builtin_amdgcn_s_setprio(1);                                        \
        FFN1_MM03(af0, af1, af2, af3);                                        \
        __builtin_amdgcn_s_setprio(0);                                        \
        if (PF) {                                                             \
            GLL16(bsn + woff + lane8, (char*)&BWR[woff]);                     \
            GLL16(bsn + woff + 512 + lane8, (char*)&BWR[woff + 512]);         \
        }                                                                     \
        af0 = LDF(ARD, am0 + 4); af1 = LDF(ARD, am0 + 5);                     \
        af2 = LDF(ARD, am0 + 6); af3 = LDF(ARD, am0 + 7);                     \
        __builtin_amdgcn_s_setprio(1);                                        \
        FFN1_MM47(af0, af1, af2, af3);                                        \
        __builtin_amdgcn_s_setprio(0);                                        \
        SCHEDB(); if (PF) { VMCNT4(); } else { VMCNT0(); } SBAR(); SCHEDB();  \
        if (PF) {                                                             \
            GLL16(asn + 8192 + woff + lane8, (char*)&AWR[8192 + woff]);       \
            GLL16(asn + 8192 + woff + 512 + lane8, (char*)&AWR[8192 + woff + 512]); \
        }                                                                     \
        bf0 = LDF(BRD, 16 + bn0); bf1 = LDF(BRD, 16 + bn0 + 1);               \
        bf2 = LDF(BRD, 16 + bn0 + 8); bf3 = LDF(BRD, 16 + bn0 + 9);           \
        af0 = LDF(ARD, 16 + am0 + 0); af1 = LDF(ARD, 16 + am0 + 1);           \
        af2 = LDF(ARD, 16 + am0 + 2); af3 = LDF(ARD, 16 + am0 + 3);           \
        __builtin_amdgcn_s_setprio(1);                                        \
        FFN1_MM03(af0, af1, af2, af3);                                        \
        __builtin_amdgcn_s_setprio(0);                                        \
        if (PF) {                                                             \
            GLL16(bsn + 8192 + woff + lane8, (char*)&BWR[8192 + woff]);       \
            GLL16(bsn + 8192 + woff + 512 + lane8, (char*)&BWR[8192 + woff + 512]); \
        }                                                                     \
        af0 = LDF(ARD, 16 + am0 + 4); af1 = LDF(ARD, 16 + am0 + 5);           \
        af2 = LDF(ARD, 16 + am0 + 6); af3 = LDF(ARD, 16 + am0 + 7);           \
        __builtin_amdgcn_s_setprio(1);                                        \
        FFN1_MM47(af0, af1, af2, af3);                                        \
        __builtin_amdgcn_s_setprio(0);                                        \
    } while (0)

__global__ __launch_bounds__(512) void k_ffn1(const unsigned short* __restrict__ xeP,
                                              const unsigned short* __restrict__ w1p,
                                              const float* __restrict__ b1,
                                              const float* __restrict__ mbias,
                                              unsigned short* __restrict__ actP) {
    const int wg = blockIdx.x;               // 704 = 8 XCD * 88
    const int e = wg & 7;
    const int rem = wg >> 3;
    const int fg = rem >> 2;                 // 0..21
    const int rt = rem & 3;                  // 0..3
    const int sgrp = e * 4 + rt;

    __shared__ unsigned short Ab0[16384];
    __shared__ unsigned short Bb0[16384];
    __shared__ unsigned short Ab1[16384];
    __shared__ unsigned short Bb1[16384];

    const int tid = threadIdx.x, lane = tid & 63, w = tid >> 6;
    const int wm = w >> 2, wn = w & 3;
    const int lane8 = lane * 8;
    const int woff = w * 1024;
    const int am0 = wm * 8, bn0 = wn * 2;

    const unsigned short* abase = xeP + ((size_t)(sgrp * NKT1) << 14);
    const unsigned short* bbase = w1p + ((size_t)((e * NFG + fg) * NKT1) << 14);

    f32x4 acc[8][4];
#pragma unroll
    for (int i = 0; i < 8; ++i)
#pragma unroll
        for (int j = 0; j < 4; ++j) acc[i][j] = (f32x4)(0.f);

    // prologue: tile 0 -> buf0, issue order {A-h0, B-h0, A-h1, B-h1}
    GLL16(abase + woff + lane8, (char*)&Ab0[woff]);
    GLL16(abase + woff + 512 + lane8, (char*)&Ab0[woff + 512]);
    GLL16(bbase + woff + lane8, (char*)&Bb0[woff]);
    GLL16(bbase + woff + 512 + lane8, (char*)&Bb0[woff + 512]);
    GLL16(abase + 8192 + woff + lane8, (char*)&Ab0[8192 + woff]);
    GLL16(abase + 8192 + woff + 512 + lane8, (char*)&Ab0[8192 + woff + 512]);
    GLL16(bbase + 8192 + woff + lane8, (char*)&Bb0[8192 + woff]);
    GLL16(bbase + 8192 + woff + 512 + lane8, (char*)&Bb0[8192 + woff + 512]);

    for (int kt = 0; kt < NKT1; kt += 2) {
        FFN1_KT(Ab0, Bb0, Ab1, Bb1, kt + 1, 1);
        FFN1_KT(Ab1, Bb1, Ab0, Bb0, kt + 2, (kt + 2) < NKT1);
    }

    // epilogue: bias + exact GELU + mult_bias -> fragment-packed act
    const float* b1e = b1 + (size_t)e * H2_;
    const float* mbe = mbias + (size_t)e * H_;
    const int colL = lane & 15, rq4 = (lane >> 4) * 4;
#pragma unroll
    for (int mi = 0; mi < 8; ++mi) {
        const int Rl = wm * 128 + mi * 16 + rq4;
#pragma unroll
        for (int vi = 0; vi < 2; ++vi) {
            const int f = fg * 128 + wn * 32 + vi * 16 + colL;
            if (f >= NKT2 * 64) continue;
            const bool real = f < H_;
            const float bv = real ? b1e[f] : 0.f;
            const float bg = real ? b1e[H_ + f] : 0.f;
            const float mv = real ? mbe[f] : 0.f;
            const int ktf = f >> 6, k32f = (f >> 5) & 1;
            const int lhi = ((f >> 3) & 3) << 4;
            const int bb = f & 7;
            const size_t cbase = ((size_t)(sgrp * NKT2 + ktf) << 14) + (k32f << 13);
#pragma unroll
            for (int j = 0; j < 4; ++j) {
                const int R = Rl + j;
                float a = 0.f;
                if (real) {
                    const float val = acc[mi][vi][j] + bv;
                    const float gt  = acc[mi][2 + vi][j] + bg;
                    a = 0.5f * gt * (1.f + erff(gt * 0.70710678118654752f)) * val * mv;
                }
                actP[cbase + ((R >> 4) << 9) + (size_t)((lhi | (R & 15)) * 8 + bb)] = f2bf(a);
            }
        }
    }
}

// ---------------- GEMM2: distinct-buffer dbuf, counted-vmcnt (measured best) ----------------
#define FFN2_MM03(AF0, AF1, AF2, AF3)                                         \
    do {                                                                      \
        acc[0][0]=MFMA16(AF0,bf0,acc[0][0]); acc[0][1]=MFMA16(AF0,bf1,acc[0][1]); \
        acc[1][0]=MFMA16(AF1,bf0,acc[1][0]); acc[1][1]=MFMA16(AF1,bf1,acc[1][1]); \
        acc[2][0]=MFMA16(AF2,bf0,acc[2][0]); acc[2][1]=MFMA16(AF2,bf1,acc[2][1]); \
        acc[3][0]=MFMA16(AF3,bf0,acc[3][0]); acc[3][1]=MFMA16(AF3,bf1,acc[3][1]); \
    } while (0)
#define FFN2_MM47(AF0, AF1, AF2, AF3)                                         \
    do {                                                                      \
        acc[4][0]=MFMA16(AF0,bf0,acc[4][0]); acc[4][1]=MFMA16(AF0,bf1,acc[4][1]); \
        acc[5][0]=MFMA16(AF1,bf0,acc[5][0]); acc[5][1]=MFMA16(AF1,bf1,acc[5][1]); \
        acc[6][0]=MFMA16(AF2,bf0,acc[6][0]); acc[6][1]=MFMA16(AF2,bf1,acc[6][1]); \
        acc[7][0]=MFMA16(AF3,bf0,acc[7][0]); acc[7][1]=MFMA16(AF3,bf1,acc[7][1]); \
    } while (0)

#define FFN2_KT(ARD, BRD, AWR, BWR, KTN, PF)                                  \
    do {                                                                      \
        const unsigned short* asn = abase + ((size_t)(KTN) << 14);            \
        const unsigned short* bsn = bbase + ((size_t)(KTN) << 13);            \
        short8 af0, af1, af2, af3, bf0, bf1;                                  \
        SCHEDB(); VMCNT3(); SBAR(); SCHEDB();                                 \
        if (PF) {                                                             \
            GLL16(asn + woff + lane8, (char*)&AWR[woff]);                     \
            GLL16(asn + woff + 512 + lane8, (char*)&AWR[woff + 512]);         \
        }                                                                     \
        bf0 = LDF(BRD, bn0); bf1 = LDF(BRD, bn0 + 1);                         \
        af0 = LDF(ARD, am0 + 0); af1 = LDF(ARD, am0 + 1);                     \
        af2 = LDF(ARD, am0 + 2); af3 = LDF(ARD, am0 + 3);                     \
        __builtin_amdgcn_s_setprio(1);                                        \
        FFN2_MM03(af0, af1, af2, af3);                                        \
        __builtin_amdgcn_s_setprio(0);                                        \
        if (PF) { GLL16(bsn + woffb + lane8, (char*)&BWR[woffb]); }           \
        af0 = LDF(ARD, am0 + 4); af1 = LDF(ARD, am0 + 5);                     \
        af2 = LDF(ARD, am0 + 6); af3 = LDF(ARD, am0 + 7);                     \
        __builtin_amdgcn_s_setprio(1);                                        \
        FFN2_MM47(af0, af1, af2, af3);                                        \
        __builtin_amdgcn_s_setprio(0);                                        \
        SCHEDB(); if (PF) { VMCNT3(); } else { VMCNT0(); } SBAR(); SCHEDB();  \
        if (PF) {                                                             \
            GLL16(asn + 8192 + woff + lane8, (char*)&AWR[8192 + woff]);       \
            GLL16(asn + 8192 + woff + 512 + lane8, (char*)&AWR[8192 + woff + 512]); \
        }                                                                     \
        bf0 = LDF(BRD, 8 + bn0); bf1 = LDF(BRD, 8 + bn0 + 1);                 \
        af0 = LDF(ARD, 16 + am0 + 0); af1 = LDF(ARD, 16 + am0 + 1);           \
        af2 = LDF(ARD, 16 + am0 + 2); af3 = LDF(ARD, 16 + am0 + 3);           \
        __builtin_amdgcn_s_setprio(1);                                        \
        FFN2_MM03(af0, af1, af2, af3);                                        \
        __builtin_amdgcn_s_setprio(0);                                        \
        if (PF) { GLL16(bsn + 4096 + woffb + lane8, (char*)&BWR[4096 + woffb]); } \
        af0 = LDF(ARD, 16 + am0 + 4); af1 = LDF(ARD, 16 + am0 + 5);           \
        af2 = LDF(ARD, 16 + am0 + 6); af3 = LDF(ARD, 16 + am0 + 7);           \
        __builtin_amdgcn_s_setprio(1);                                        \
        FFN2_MM47(af0, af1, af2, af3);                                        \
        __builtin_amdgcn_s_setprio(0);                                        \
    } while (0)

__global__ __launch_bounds__(512) void k_ffn2(const unsigned short* __restrict__ actP,
                                              const unsigned short* __restrict__ w2p,
                                              const float* __restrict__ b2,
                                              unsigned short* __restrict__ oute) {
    const int wg = blockIdx.x;               // 256 = 8 XCD * 32
    const int e = wg & 7;
    const int rem = wg >> 3;
    const int nt = rem >> 2;                 // 0..7
    const int mt = rem & 3;                  // 0..3
    const int sgrp = e * 4 + mt;

    __shared__ unsigned short Ab0[16384];
    __shared__ unsigned short Bb0[8192];
    __shared__ unsigned short Ab1[16384];
    __shared__ unsigned short Bb1[8192];

    const int tid = threadIdx.x, lane = tid & 63, w = tid >> 6;
    const int wm = w >> 2, wn = w & 3;
    const int lane8 = lane * 8;
    const int woff = w * 1024;
    const int woffb = w * 512;
    const int am0 = wm * 8, bn0 = wn * 2;

    const unsigned short* abase = actP + ((size_t)(sgrp * NKT2) << 14);
    const unsigned short* bbase = w2p + ((size_t)((e * 8 + nt) * NKT2) << 13);

    f32x4 acc[8][2];
#pragma unroll
    for (int i = 0; i < 8; ++i)
#pragma unroll
        for (int j = 0; j < 2; ++j) acc[i][j] = (f32x4)(0.f);

    // prologue: tile 0 -> buf0, issue order {A-h0(2), B-h0(1), A-h1(2), B-h1(1)}
    GLL16(abase + woff + lane8, (char*)&Ab0[woff]);
    GLL16(abase + woff + 512 + lane8, (char*)&Ab0[woff + 512]);
    GLL16(bbase + woffb + lane8, (char*)&Bb0[woffb]);
    GLL16(abase + 8192 + woff + lane8, (char*)&Ab0[8192 + woff]);
    GLL16(abase + 8192 + woff + 512 + lane8, (char*)&Ab0[8192 + woff + 512]);
    GLL16(bbase + 4096 + woffb + lane8, (char*)&Bb0[4096 + woffb]);

    for (int kt = 0; kt < NKT2 - 1; kt += 2) {
        FFN2_KT(Ab0, Bb0, Ab1, Bb1, kt + 1, 1);
        FFN2_KT(Ab1, Bb1, Ab0, Bb0, kt + 2, (kt + 2) < NKT2);
    }
    FFN2_KT(Ab0, Bb0, Ab1, Bb1, NKT2, 0);    // kt = 42 reads buf0, no prefetch

    const float* b2e = b2 + (size_t)e * D_;
    const int colL = lane & 15, rq4 = (lane >> 4) * 4;
#pragma unroll
    for (int mi = 0; mi < 8; ++mi) {
#pragma unroll
        for (int vi = 0; vi < 2; ++vi) {
            const int d = nt * 128 + wn * 32 + vi * 16 + colL;
            const float bb2 = b2e[d];
#pragma unroll
            for (int j = 0; j < 4; ++j) {
                const int R = mt * 256 + wm * 128 + mi * 16 + rq4 + j;
                oute[((size_t)(e * 1024 + R) << 10) + d] = f2bf(acc[mi][vi][j] + bb2);
            }
        }
    }
}

// ---------------- combine (bf16 oute) ----------------
__global__ __launch_bounds__(256) void k_comb(const unsigned short* __restrict__ oute,
                                              const int* __restrict__ sot,
                                              const float* __restrict__ tokG,
                                              float* __restrict__ out) {
    const int bt = blockIdx.x;
    const int t = threadIdx.x;
    const int s0 = sot[bt], s1 = sot[NTOK + bt];
    const float g0 = tokG[bt], g1 = tokG[NTOK + bt];
    float r0 = 0.f, r1 = 0.f, r2 = 0.f, r3 = 0.f;
    if (s0 >= 0) {
        const ushort4 v = *reinterpret_cast<const ushort4*>(oute + ((size_t)s0 << 10) + t * 4);
        r0 += g0 * bf2f(v.x); r1 += g0 * bf2f(v.y); r2 += g0 * bf2f(v.z); r3 += g0 * bf2f(v.w);
    }
    if (s1 >= 0) {
        const ushort4 v = *reinterpret_cast<const ushort4*>(oute + ((size_t)s1 << 10) + t * 4);
        r0 += g1 * bf2f(v.x); r1 += g1 * bf2f(v.y); r2 += g1 * bf2f(v.z); r3 += g1 * bf2f(v.w);
    }
    float4 o; o.x = r0; o.y = r1; o.z = r2; o.w = r3;
    *reinterpret_cast<float4*>(out + ((size_t)bt << 10) + t * 4) = o;
}

extern "C" void kernel_launch(void* const* d_in, const int* in_sizes, int n_in,
                              void* d_out, int out_size, void* d_ws, size_t ws_size,
                              hipStream_t stream) {
    const float* x     = (const float*)d_in[0];
    const float* route = (const float*)d_in[1];
    const float* gw    = (const float*)d_in[2];
    const float* w1    = (const float*)d_in[3];
    const float* b1    = (const float*)d_in[4];
    const float* mb    = (const float*)d_in[5];
    const float* w2    = (const float*)d_in[6];
    const float* b2    = (const float*)d_in[7];
    float* out = (float*)d_out;

    char* ws = (char*)d_ws;
    int*   tokE = (int*)(ws + 0);
    float* tokG = (float*)(ws + 32768);
    int*   tokR = (int*)(ws + 65536);
    int*   sot  = (int*)(ws + 81920);
    int*   tos  = (int*)(ws + 114688);
    unsigned short* xeP  = (unsigned short*)(ws + 147456);      // 16.78 MB, end 16,924,672
    unsigned short* actP = (unsigned short*)(ws + 16924672);    // 45.09 MB, end 62,013,440
    unsigned short* w1p  = (unsigned short*)(ws + 62013440);    // 92.27 MB, end 154,288,128 (dead after ffn1)
    unsigned short* w2p  = (unsigned short*)(ws + 62013440);    // 45.09 MB overlay (written after ffn1)
    unsigned short* oute = (unsigned short*)(ws + 107102208);   // 16.78 MB overlay, end 123,879,424

    k_cvt1<<<dim3(NFG, NKT1, 8), 256, 0, stream>>>(w1, w1p);
    k_gate<<<NTOK / 4, 256, 0, stream>>>(x, route, gw, tokE, tokG, tokR, sot);
    k_pos<<<E_ * B_, 256, 0, stream>>>(tokE, tokG, tokR, sot, tos);
    k_disp<<<NSLOT / 2, 256, 0, stream>>>(x, tos, xeP);
    k_ffn1<<<704, 512, 0, stream>>>(xeP, w1p, b1, mb, actP);
    k_cvt2<<<dim3(NKT2, 8, 8), 256, 0, stream>>>(w2, w2p);      // after ffn1: w2p overlays w1p
    k_ffn2<<<256, 512, 0, stream>>>(actP, w2p, b2, oute);
    k_comb<<<NTOK, 256, 0, stream>>>(oute, sot, tokG, out);
}